// Round 1
// baseline (320.888 us; speedup 1.0000x reference)
//
#include <hip/hip_runtime.h>
#include <hip/hip_bf16.h>
#include <cstdint>
#include <cstddef>

// Problem constants
#define BATCH 2
#define SEQ   2048
#define DM    1024
#define NH    16
#define DK    64
#define LOG2E 1.4426950408889634f

typedef __attribute__((ext_vector_type(8))) short short8;   // 8 bf16 = 4 VGPRs (MFMA A/B frag)
typedef __attribute__((ext_vector_type(4))) float f32x4;    // MFMA C/D frag

// ---------------------------------------------------------------- helpers
__device__ __forceinline__ void gload_lds16(const __hip_bfloat16* g, __hip_bfloat16* l) {
  __builtin_amdgcn_global_load_lds((const __attribute__((address_space(1))) void*)g,
                                   (__attribute__((address_space(3))) void*)l, 16, 0, 0);
}

// ---------------------------------------------------------------- cast fp32 -> bf16
__global__ void cast_f32_bf16(const float* __restrict__ src, __hip_bfloat16* __restrict__ dst, int n) {
  int i = (blockIdx.x * 256 + threadIdx.x) * 4;
  if (i >= n) return;
  float4 v = *(const float4*)(src + i);
  dst[i + 0] = __float2bfloat16(v.x);
  dst[i + 1] = __float2bfloat16(v.y);
  dst[i + 2] = __float2bfloat16(v.z);
  dst[i + 3] = __float2bfloat16(v.w);
}

// ---------------------------------------------------------------- GEMM: C[m,n] = sum_k A[m,k]*Bw[n,k]
// m97 structure: 128x128 tile, BK=32, 4 waves (2x2), each wave 64x64 = 4x4 16x16 frags.
template<bool F32OUT>
__global__ __launch_bounds__(256)
void gemm_bt(const __hip_bfloat16* __restrict__ A,
             const __hip_bfloat16* __restrict__ Bw,
             void* __restrict__ Cv, int M, int N, int K) {
  __shared__ __hip_bfloat16 As[128 * 32];
  __shared__ __hip_bfloat16 Bs[128 * 32];
  const int tid  = threadIdx.x;
  const int lane = tid & 63;
  const int w    = tid >> 6;        // wave 0..3
  const int wr   = w >> 1, wc = w & 1;
  const int g    = lane >> 4;       // 0..3  (k-subgroup)
  const int lr   = lane & 15;
  const int bm0  = blockIdx.y * 128;
  const int bn0  = blockIdx.x * 128;

  f32x4 acc[4][4] = {};

  // staging geometry: chunk c = w*2+it covers LDS bytes c*1024..; lane l -> row c*16 + l/4, col (l&3)*8
  const int strow = lane >> 2;      // 0..15 within chunk
  const int stcol = (lane & 3) * 8; // 0,8,16,24

  for (int kt = 0; kt < K; kt += 32) {
    #pragma unroll
    for (int it = 0; it < 2; ++it) {
      int c   = w * 2 + it;
      int row = c * 16 + strow;
      gload_lds16(A  + (size_t)(bm0 + row) * K + kt + stcol, As + row * 32 + stcol);
      gload_lds16(Bw + (size_t)(bn0 + row) * K + kt + stcol, Bs + row * 32 + stcol);
    }
    __syncthreads();   // drains vmcnt -> LDS tiles valid
    short8 a[4], b[4];
    #pragma unroll
    for (int m = 0; m < 4; ++m)
      a[m] = *(const short8*)(As + (wr * 64 + m * 16 + lr) * 32 + g * 8);
    #pragma unroll
    for (int n = 0; n < 4; ++n)
      b[n] = *(const short8*)(Bs + (wc * 64 + n * 16 + lr) * 32 + g * 8);
    #pragma unroll
    for (int m = 0; m < 4; ++m)
      #pragma unroll
      for (int n = 0; n < 4; ++n)
        acc[m][n] = __builtin_amdgcn_mfma_f32_16x16x32_bf16(a[m], b[n], acc[m][n], 0, 0, 0);
    __syncthreads();
  }

  // epilogue: C layout col=lane&15, row=(lane>>4)*4+r
  #pragma unroll
  for (int m = 0; m < 4; ++m)
    #pragma unroll
    for (int n = 0; n < 4; ++n) {
      int col = bn0 + wc * 64 + n * 16 + lr;
      #pragma unroll
      for (int r = 0; r < 4; ++r) {
        int row = bm0 + wr * 64 + m * 16 + g * 4 + r;
        float v = acc[m][n][r];
        if (F32OUT) ((float*)Cv)[(size_t)row * N + col] = v;
        else        ((__hip_bfloat16*)Cv)[(size_t)row * N + col] = __float2bfloat16(v);
      }
    }
}

// ---------------------------------------------------------------- RoPE in place on QKV (Q scaled by 1/8)
__global__ void rope_kernel(__hip_bfloat16* __restrict__ qkv, const int* __restrict__ pos) {
  int idx = blockIdx.x * 256 + threadIdx.x;   // one thread per (row, head, pair)
  if (idx >= BATCH * SEQ * NH * (DK / 2)) return;
  int m  = idx >> 9;          // row 0..4095 (NH*DK/2 = 512)
  int hp = idx & 511;
  int h  = hp >> 5;           // head
  int pk = hp & 31;           // pair index
  int s  = m & (SEQ - 1);
  float p   = (float)pos[s];
  // inv_freq = 10000^(-pk/32) = 2^(-pk*log2(10000)/32)
  float ang = p * exp2f(-(float)pk * 0.415241011860920f);
  float cv, sv;
  __sincosf(ang, &sv, &cv);
  size_t base = (size_t)m * (3 * DM) + h * DK + 2 * pk;
  float q0 = __bfloat162float(qkv[base]),        q1 = __bfloat162float(qkv[base + 1]);
  qkv[base]     = __float2bfloat16((q0 * cv - q1 * sv) * 0.125f);
  qkv[base + 1] = __float2bfloat16((q0 * sv + q1 * cv) * 0.125f);
  float k0 = __bfloat162float(qkv[base + DM]),   k1 = __bfloat162float(qkv[base + DM + 1]);
  qkv[base + DM]     = __float2bfloat16(k0 * cv - k1 * sv);
  qkv[base + DM + 1] = __float2bfloat16(k0 * sv + k1 * cv);
}

// ---------------------------------------------------------------- flash attention
// grid: (qblocks=32, heads=16, batch=2), 256 threads = 4 waves x 16 q-rows, KV tile = 32
__global__ __launch_bounds__(256)
void flash_attn(const __hip_bfloat16* __restrict__ qkv, __hip_bfloat16* __restrict__ outb) {
  __shared__ __hip_bfloat16 Ks[32 * 64];
  __shared__ __hip_bfloat16 Vt[64 * 32];      // Vt[d][k]
  __shared__ __hip_bfloat16 Ps[4][16 * 32];   // per-wave P tile
  const int qblk = blockIdx.x, h = blockIdx.y, b = blockIdx.z;
  const int tid = threadIdx.x, lane = tid & 63, w = tid >> 6;
  const int g = lane >> 4, lr = lane & 15;

  // Q fragments (held in regs for whole loop); Q pre-scaled by 1/8 in rope
  const size_t rowQ = (size_t)(b * SEQ + qblk * 64 + w * 16 + lr);
  short8 aq0 = *(const short8*)(qkv + rowQ * (3 * DM) + h * DK + g * 8);
  short8 aq1 = *(const short8*)(qkv + rowQ * (3 * DM) + h * DK + 32 + g * 8);

  f32x4 acc[4] = {};
  float m_run[4], l_run[4];
  #pragma unroll
  for (int r = 0; r < 4; ++r) { m_run[r] = -1e30f; l_run[r] = 0.f; }

  const int qrow_base = qblk * 64 + w * 16;
  const int ntiles    = qblk * 2 + 2;   // covers k <= qblk*64+63

  const __hip_bfloat16* Kbase = qkv + (size_t)b * SEQ * (3 * DM) + DM     + h * DK;
  const __hip_bfloat16* Vbase = qkv + (size_t)b * SEQ * (3 * DM) + 2 * DM + h * DK;

  const int skr = tid >> 3;        // staging: k-row 0..31
  const int sc8 = (tid & 7) * 8;   // d-col 0..56

  for (int t = 0; t < ntiles; ++t) {
    // ---- stage K (row-major) and V (transposed) into LDS
    {
      size_t koff = (size_t)(t * 32 + skr) * (3 * DM) + sc8;
      *(short8*)(Ks + skr * 64 + sc8) = *(const short8*)(Kbase + koff);
      short8 vv = *(const short8*)(Vbase + koff);
      #pragma unroll
      for (int j = 0; j < 8; ++j)
        Vt[(sc8 + j) * 32 + skr] = ((const __hip_bfloat16*)&vv)[j];
    }
    __syncthreads();

    // ---- scores: S[16q x 32k] (two 16-col groups)
    f32x4 sc[2];
    #pragma unroll
    for (int c = 0; c < 2; ++c) {
      short8 kb0 = *(const short8*)(Ks + (c * 16 + lr) * 64 + g * 8);
      short8 kb1 = *(const short8*)(Ks + (c * 16 + lr) * 64 + 32 + g * 8);
      f32x4 s = {};
      s = __builtin_amdgcn_mfma_f32_16x16x32_bf16(aq0, kb0, s, 0, 0, 0);
      s = __builtin_amdgcn_mfma_f32_16x16x32_bf16(aq1, kb1, s, 0, 0, 0);
      sc[c] = s;
    }

    // ---- causal mask + online softmax (row = g*4+r, col = c*16+lr)
    float rowmax[4];
    #pragma unroll
    for (int r = 0; r < 4; ++r) {
      int q = qrow_base + g * 4 + r;
      #pragma unroll
      for (int c = 0; c < 2; ++c) {
        int k = t * 32 + c * 16 + lr;
        if (k > q) sc[c][r] = -1e30f;
      }
      rowmax[r] = fmaxf(sc[0][r], sc[1][r]);
    }
    #pragma unroll
    for (int d = 1; d < 16; d <<= 1)
      #pragma unroll
      for (int r = 0; r < 4; ++r)
        rowmax[r] = fmaxf(rowmax[r], __shfl_xor(rowmax[r], d, 64));

    float p0[4], p1[4], rsum[4], fac[4];
    #pragma unroll
    for (int r = 0; r < 4; ++r) {
      float mn = fmaxf(m_run[r], rowmax[r]);
      fac[r] = exp2f((m_run[r] - mn) * LOG2E);
      p0[r]  = exp2f((sc[0][r] - mn) * LOG2E);
      p1[r]  = exp2f((sc[1][r] - mn) * LOG2E);
      m_run[r] = mn;
      rsum[r]  = p0[r] + p1[r];
    }
    #pragma unroll
    for (int d = 1; d < 16; d <<= 1)
      #pragma unroll
      for (int r = 0; r < 4; ++r)
        rsum[r] += __shfl_xor(rsum[r], d, 64);
    #pragma unroll
    for (int r = 0; r < 4; ++r) l_run[r] = l_run[r] * fac[r] + rsum[r];

    // ---- P -> LDS (per-wave private), re-fragment for PV
    __hip_bfloat16* Pw = &Ps[w][0];
    #pragma unroll
    for (int r = 0; r < 4; ++r) {
      int row = g * 4 + r;
      Pw[row * 32 + lr]      = __float2bfloat16(p0[r]);
      Pw[row * 32 + 16 + lr] = __float2bfloat16(p1[r]);
    }
    // rescale accumulators
    #pragma unroll
    for (int ch = 0; ch < 4; ++ch)
      #pragma unroll
      for (int r = 0; r < 4; ++r) acc[ch][r] *= fac[r];

    // ---- PV: O[16q x 64d] += P[16x32] * V[32x64]
    short8 pa = *(const short8*)(Pw + lr * 32 + g * 8);
    #pragma unroll
    for (int ch = 0; ch < 4; ++ch) {
      short8 vb = *(const short8*)(Vt + (ch * 16 + lr) * 32 + g * 8);
      acc[ch] = __builtin_amdgcn_mfma_f32_16x16x32_bf16(pa, vb, acc[ch], 0, 0, 0);
    }
    __syncthreads();
  }

  // ---- epilogue: normalize, write [B,S,H*DK] bf16
  #pragma unroll
  for (int ch = 0; ch < 4; ++ch)
    #pragma unroll
    for (int r = 0; r < 4; ++r) {
      int q = qrow_base + g * 4 + r;
      float v = acc[ch][r] / l_run[r];
      outb[(size_t)(b * SEQ + q) * DM + h * DK + ch * 16 + lr] = __float2bfloat16(v);
    }
}

// ---------------------------------------------------------------- launch
extern "C" void kernel_launch(void* const* d_in, const int* in_sizes, int n_in,
                              void* d_out, int out_size, void* d_ws, size_t ws_size,
                              hipStream_t stream) {
  const float* x  = (const float*)d_in[0];
  const float* Wq = (const float*)d_in[1];
  const float* Wk = (const float*)d_in[2];
  const float* Wv = (const float*)d_in[3];
  const float* Wo = (const float*)d_in[4];
  const int*   tp = (const int*)d_in[5];
  float* out = (float*)d_out;

  char* ws = (char*)d_ws;
  __hip_bfloat16* xb    = (__hip_bfloat16*)(ws);                         // 4096x1024   (8 MB)
  __hip_bfloat16* wqkv  = (__hip_bfloat16*)(ws + (8u  << 20));           // 3072x1024   (6 MB)
  __hip_bfloat16* wob   = (__hip_bfloat16*)(ws + (14u << 20));           // 1024x1024   (2 MB)
  __hip_bfloat16* qkv   = (__hip_bfloat16*)(ws + (16u << 20));           // 4096x3072  (24 MB)
  __hip_bfloat16* attnb = (__hip_bfloat16*)(ws + (40u << 20));           // 4096x1024   (8 MB)

  const int NX = BATCH * SEQ * DM;   // 4194304
  const int NW = DM * DM;            // 1048576

  cast_f32_bf16<<<NX / 1024, 256, 0, stream>>>(x,  xb,          NX);
  cast_f32_bf16<<<NW / 1024, 256, 0, stream>>>(Wq, wqkv,        NW);
  cast_f32_bf16<<<NW / 1024, 256, 0, stream>>>(Wk, wqkv + NW,   NW);
  cast_f32_bf16<<<NW / 1024, 256, 0, stream>>>(Wv, wqkv + 2*NW, NW);
  cast_f32_bf16<<<NW / 1024, 256, 0, stream>>>(Wo, wob,         NW);

  // QKV = xb @ wqkv^T : [4096, 3072]
  gemm_bt<false><<<dim3(3 * DM / 128, BATCH * SEQ / 128), 256, 0, stream>>>(
      xb, wqkv, (void*)qkv, BATCH * SEQ, 3 * DM, DM);

  rope_kernel<<<(BATCH * SEQ * NH * (DK / 2)) / 256, 256, 0, stream>>>(qkv, tp);

  flash_attn<<<dim3(SEQ / 64, NH, BATCH), 256, 0, stream>>>(qkv, attnb);

  // out = attnb @ wob^T : [4096, 1024] fp32
  gemm_bt<true><<<dim3(DM / 128, BATCH * SEQ / 128), 256, 0, stream>>>(
      attnb, wob, (void*)out, BATCH * SEQ, DM, DM);
}

// Round 2
// 240.148 us; speedup vs baseline: 1.3362x; 1.3362x over previous
//
#include <hip/hip_runtime.h>
#include <hip/hip_bf16.h>
#include <cstdint>
#include <cstddef>

// Problem constants
#define BATCH 2
#define SEQ   2048
#define DM    1024
#define NH    16
#define DK    64
#define LOG2E 1.4426950408889634f

typedef __attribute__((ext_vector_type(8))) short short8;   // 8 bf16 = 4 VGPRs (MFMA A/B frag)
typedef __attribute__((ext_vector_type(4))) float f32x4;    // MFMA C/D frag

// ---------------------------------------------------------------- helpers
__device__ __forceinline__ void gload_lds16(const __hip_bfloat16* g, __hip_bfloat16* l) {
  __builtin_amdgcn_global_load_lds((const __attribute__((address_space(1))) void*)g,
                                   (__attribute__((address_space(3))) void*)l, 16, 0, 0);
}

// ---------------------------------------------------------------- cast fp32 -> bf16
__global__ void cast_f32_bf16(const float* __restrict__ src, __hip_bfloat16* __restrict__ dst, int n) {
  int i = (blockIdx.x * 256 + threadIdx.x) * 4;
  if (i >= n) return;
  float4 v = *(const float4*)(src + i);
  dst[i + 0] = __float2bfloat16(v.x);
  dst[i + 1] = __float2bfloat16(v.y);
  dst[i + 2] = __float2bfloat16(v.z);
  dst[i + 3] = __float2bfloat16(v.w);
}

// ---------------------------------------------------------------- GEMM: C[m,n] = sum_k A[m,k]*Bw[n,k]
// m97 structure: 128x128 tile, BK=32, 4 waves (2x2), each wave 64x64 = 4x4 16x16 frags.
template<bool F32OUT>
__global__ __launch_bounds__(256)
void gemm_bt(const __hip_bfloat16* __restrict__ A,
             const __hip_bfloat16* __restrict__ Bw,
             void* __restrict__ Cv, int M, int N, int K) {
  __shared__ __hip_bfloat16 As[128 * 32];
  __shared__ __hip_bfloat16 Bs[128 * 32];
  const int tid  = threadIdx.x;
  const int lane = tid & 63;
  const int w    = tid >> 6;        // wave 0..3
  const int wr   = w >> 1, wc = w & 1;
  const int g    = lane >> 4;       // 0..3  (k-subgroup)
  const int lr   = lane & 15;
  const int bm0  = blockIdx.y * 128;
  const int bn0  = blockIdx.x * 128;

  f32x4 acc[4][4] = {};

  // staging geometry: chunk c = w*2+it covers LDS bytes c*1024..; lane l -> row c*16 + l/4, col (l&3)*8
  const int strow = lane >> 2;      // 0..15 within chunk
  const int stcol = (lane & 3) * 8; // 0,8,16,24

  for (int kt = 0; kt < K; kt += 32) {
    #pragma unroll
    for (int it = 0; it < 2; ++it) {
      int c   = w * 2 + it;
      int row = c * 16 + strow;
      gload_lds16(A  + (size_t)(bm0 + row) * K + kt + stcol, As + row * 32 + stcol);
      gload_lds16(Bw + (size_t)(bn0 + row) * K + kt + stcol, Bs + row * 32 + stcol);
    }
    __syncthreads();   // drains vmcnt -> LDS tiles valid
    short8 a[4], b[4];
    #pragma unroll
    for (int m = 0; m < 4; ++m)
      a[m] = *(const short8*)(As + (wr * 64 + m * 16 + lr) * 32 + g * 8);
    #pragma unroll
    for (int n = 0; n < 4; ++n)
      b[n] = *(const short8*)(Bs + (wc * 64 + n * 16 + lr) * 32 + g * 8);
    #pragma unroll
    for (int m = 0; m < 4; ++m)
      #pragma unroll
      for (int n = 0; n < 4; ++n)
        acc[m][n] = __builtin_amdgcn_mfma_f32_16x16x32_bf16(a[m], b[n], acc[m][n], 0, 0, 0);
    __syncthreads();
  }

  // epilogue: C layout col=lane&15, row=(lane>>4)*4+r
  #pragma unroll
  for (int m = 0; m < 4; ++m)
    #pragma unroll
    for (int n = 0; n < 4; ++n) {
      int col = bn0 + wc * 64 + n * 16 + lr;
      #pragma unroll
      for (int r = 0; r < 4; ++r) {
        int row = bm0 + wr * 64 + m * 16 + g * 4 + r;
        float v = acc[m][n][r];
        if (F32OUT) ((float*)Cv)[(size_t)row * N + col] = v;
        else        ((__hip_bfloat16*)Cv)[(size_t)row * N + col] = __float2bfloat16(v);
      }
    }
}

// ---------------------------------------------------------------- RoPE in place on QKV (Q scaled by 1/8)
__global__ void rope_kernel(__hip_bfloat16* __restrict__ qkv, const int* __restrict__ pos) {
  int idx = blockIdx.x * 256 + threadIdx.x;   // one thread per (row, head, pair)
  if (idx >= BATCH * SEQ * NH * (DK / 2)) return;
  int m  = idx >> 9;          // row 0..4095 (NH*DK/2 = 512)
  int hp = idx & 511;
  int h  = hp >> 5;           // head
  int pk = hp & 31;           // pair index
  int s  = m & (SEQ - 1);
  float p   = (float)pos[s];
  // inv_freq = 10000^(-pk/32) = 2^(-pk*log2(10000)/32)
  float ang = p * exp2f(-(float)pk * 0.415241011860920f);
  float cv, sv;
  __sincosf(ang, &sv, &cv);
  size_t base = (size_t)m * (3 * DM) + h * DK + 2 * pk;
  float q0 = __bfloat162float(qkv[base]),        q1 = __bfloat162float(qkv[base + 1]);
  qkv[base]     = __float2bfloat16((q0 * cv - q1 * sv) * 0.125f);
  qkv[base + 1] = __float2bfloat16((q0 * sv + q1 * cv) * 0.125f);
  float k0 = __bfloat162float(qkv[base + DM]),   k1 = __bfloat162float(qkv[base + DM + 1]);
  qkv[base + DM]     = __float2bfloat16(k0 * cv - k1 * sv);
  qkv[base + DM + 1] = __float2bfloat16(k0 * sv + k1 * cv);
}

// ---------------------------------------------------------------- flash attention
// grid: (qblocks=32 reversed, heads=16, batch=2), 256 threads = 4 waves x 16 q-rows
// KV tile = 64; K/Vt/P LDS all XOR-swizzled (elem ^= (row&7)<<3) to kill bank conflicts.
__global__ __launch_bounds__(256)
void flash_attn(const __hip_bfloat16* __restrict__ qkv, __hip_bfloat16* __restrict__ outb) {
  __shared__ __hip_bfloat16 Ks[64 * 64];       // K[k][d], swizzled
  __shared__ __hip_bfloat16 Vt[64 * 64];       // V^T[d][k], swizzled
  __shared__ __hip_bfloat16 Ps[4][16 * 64];    // per-wave P[q][k], swizzled
  const int qblk = (int)gridDim.x - 1 - blockIdx.x;   // longest blocks dispatch first
  const int h = blockIdx.y, b = blockIdx.z;
  const int tid = threadIdx.x, lane = tid & 63, w = tid >> 6;
  const int g = lane >> 4, lr = lane & 15;

  // Q fragments (held in regs for whole loop); Q pre-scaled by 1/8 in rope
  const size_t rowQ = (size_t)(b * SEQ + qblk * 64 + w * 16 + lr);
  short8 aq0 = *(const short8*)(qkv + rowQ * (3 * DM) + h * DK + g * 8);
  short8 aq1 = *(const short8*)(qkv + rowQ * (3 * DM) + h * DK + 32 + g * 8);

  f32x4 acc[4] = {};
  float m_run[4], l_run[4];
  #pragma unroll
  for (int r = 0; r < 4; ++r) { m_run[r] = -1e30f; l_run[r] = 0.f; }

  const int qrow_base = qblk * 64 + w * 16;
  const int ntiles    = qblk + 1;   // 64-wide KV tiles up to and including diagonal

  const __hip_bfloat16* Kbase = qkv + (size_t)b * SEQ * (3 * DM) + DM     + h * DK;
  const __hip_bfloat16* Vbase = qkv + (size_t)b * SEQ * (3 * DM) + 2 * DM + h * DK;

  // staging geometry
  const int kst_row = tid >> 3;        // 0..31  (K: 2 halves of 32 rows)
  const int kst_col = (tid & 7) * 8;   // 0..56
  const int vst_k   = tid & 63;        // V: k = lane-spread -> transpose writes hit all banks
  const int vst_d0  = (tid >> 6) * 16; // each wave covers 16 d-columns

  for (int t = 0; t < ntiles; ++t) {
    // ---- stage K rows (vectorized, swizzled)
    #pragma unroll
    for (int half = 0; half < 2; ++half) {
      int r = kst_row + half * 32;
      short8 kv = *(const short8*)(Kbase + (size_t)(t * 64 + r) * (3 * DM) + kst_col);
      *(short8*)(Ks + ((r * 64 + kst_col) ^ ((r & 7) << 3))) = kv;
    }
    // ---- stage V transposed (scalar writes; k in lane -> banks spread via k>>1)
    #pragma unroll
    for (int half = 0; half < 2; ++half) {
      int d0 = vst_d0 + half * 8;
      short8 vv = *(const short8*)(Vbase + (size_t)(t * 64 + vst_k) * (3 * DM) + d0);
      #pragma unroll
      for (int j = 0; j < 8; ++j) {
        int d = d0 + j;
        Vt[(d * 64 + vst_k) ^ ((d & 7) << 3)] = ((const __hip_bfloat16*)&vv)[j];
      }
    }
    __syncthreads();

    // ---- scores: S[16q x 64k]
    f32x4 sc[4];
    #pragma unroll
    for (int c = 0; c < 4; ++c) {
      int krow = c * 16 + lr;
      int sw = (krow & 7) << 3;
      short8 kb0 = *(const short8*)(Ks + ((krow * 64 + g * 8) ^ sw));
      short8 kb1 = *(const short8*)(Ks + ((krow * 64 + 32 + g * 8) ^ sw));
      f32x4 s = {};
      s = __builtin_amdgcn_mfma_f32_16x16x32_bf16(aq0, kb0, s, 0, 0, 0);
      s = __builtin_amdgcn_mfma_f32_16x16x32_bf16(aq1, kb1, s, 0, 0, 0);
      sc[c] = s;
    }

    // ---- causal mask: only the diagonal tile needs it (wave-uniform branch)
    if (t == qblk) {
      #pragma unroll
      for (int r = 0; r < 4; ++r) {
        int q = qrow_base + g * 4 + r;
        #pragma unroll
        for (int c = 0; c < 4; ++c) {
          int k = t * 64 + c * 16 + lr;
          if (k > q) sc[c][r] = -1e30f;
        }
      }
    }

    // ---- online softmax (row = g*4+r spread over 16 lanes)
    float rowmax[4];
    #pragma unroll
    for (int r = 0; r < 4; ++r)
      rowmax[r] = fmaxf(fmaxf(sc[0][r], sc[1][r]), fmaxf(sc[2][r], sc[3][r]));
    #pragma unroll
    for (int d = 1; d < 16; d <<= 1)
      #pragma unroll
      for (int r = 0; r < 4; ++r)
        rowmax[r] = fmaxf(rowmax[r], __shfl_xor(rowmax[r], d, 64));

    float p[4][4], fac[4], rsum[4];
    #pragma unroll
    for (int r = 0; r < 4; ++r) {
      float mn = fmaxf(m_run[r], rowmax[r]);
      fac[r] = exp2f((m_run[r] - mn) * LOG2E);
      m_run[r] = mn;
      float s = 0.f;
      #pragma unroll
      for (int c = 0; c < 4; ++c) {
        p[c][r] = exp2f((sc[c][r] - mn) * LOG2E);
        s += p[c][r];
      }
      rsum[r] = s;
    }
    #pragma unroll
    for (int d = 1; d < 16; d <<= 1)
      #pragma unroll
      for (int r = 0; r < 4; ++r)
        rsum[r] += __shfl_xor(rsum[r], d, 64);
    #pragma unroll
    for (int r = 0; r < 4; ++r) l_run[r] = l_run[r] * fac[r] + rsum[r];

    // ---- P -> per-wave LDS (swizzled), re-fragment for PV
    __hip_bfloat16* Pw = &Ps[w][0];
    #pragma unroll
    for (int r = 0; r < 4; ++r) {
      int row = g * 4 + r;
      int sw = (row & 7) << 3;
      #pragma unroll
      for (int c = 0; c < 4; ++c)
        Pw[(row * 64 + c * 16 + lr) ^ sw] = __float2bfloat16(p[c][r]);
    }
    // rescale accumulators
    #pragma unroll
    for (int ch = 0; ch < 4; ++ch)
      #pragma unroll
      for (int r = 0; r < 4; ++r) acc[ch][r] *= fac[r];

    // ---- PV: O[16q x 64d] += P[16x64] * V[64x64]
    #pragma unroll
    for (int kc = 0; kc < 2; ++kc) {
      short8 pa = *(const short8*)(Pw + ((lr * 64 + kc * 32 + g * 8) ^ ((lr & 7) << 3)));
      #pragma unroll
      for (int ch = 0; ch < 4; ++ch) {
        int vrow = ch * 16 + lr;
        short8 vb = *(const short8*)(Vt + ((vrow * 64 + kc * 32 + g * 8) ^ ((vrow & 7) << 3)));
        acc[ch] = __builtin_amdgcn_mfma_f32_16x16x32_bf16(pa, vb, acc[ch], 0, 0, 0);
      }
    }
    __syncthreads();
  }

  // ---- epilogue: normalize, write [B,S,H*DK] bf16
  #pragma unroll
  for (int ch = 0; ch < 4; ++ch)
    #pragma unroll
    for (int r = 0; r < 4; ++r) {
      int q = qrow_base + g * 4 + r;
      float v = acc[ch][r] / l_run[r];
      outb[(size_t)(b * SEQ + q) * DM + h * DK + ch * 16 + lr] = __float2bfloat16(v);
    }
}

// ---------------------------------------------------------------- launch
extern "C" void kernel_launch(void* const* d_in, const int* in_sizes, int n_in,
                              void* d_out, int out_size, void* d_ws, size_t ws_size,
                              hipStream_t stream) {
  const float* x  = (const float*)d_in[0];
  const float* Wq = (const float*)d_in[1];
  const float* Wk = (const float*)d_in[2];
  const float* Wv = (const float*)d_in[3];
  const float* Wo = (const float*)d_in[4];
  const int*   tp = (const int*)d_in[5];
  float* out = (float*)d_out;

  char* ws = (char*)d_ws;
  __hip_bfloat16* xb    = (__hip_bfloat16*)(ws);                         // 4096x1024   (8 MB)
  __hip_bfloat16* wqkv  = (__hip_bfloat16*)(ws + (8u  << 20));           // 3072x1024   (6 MB)
  __hip_bfloat16* wob   = (__hip_bfloat16*)(ws + (14u << 20));           // 1024x1024   (2 MB)
  __hip_bfloat16* qkv   = (__hip_bfloat16*)(ws + (16u << 20));           // 4096x3072  (24 MB)
  __hip_bfloat16* attnb = (__hip_bfloat16*)(ws + (40u << 20));           // 4096x1024   (8 MB)

  const int NX = BATCH * SEQ * DM;   // 4194304
  const int NW = DM * DM;            // 1048576

  cast_f32_bf16<<<NX / 1024, 256, 0, stream>>>(x,  xb,          NX);
  cast_f32_bf16<<<NW / 1024, 256, 0, stream>>>(Wq, wqkv,        NW);
  cast_f32_bf16<<<NW / 1024, 256, 0, stream>>>(Wk, wqkv + NW,   NW);
  cast_f32_bf16<<<NW / 1024, 256, 0, stream>>>(Wv, wqkv + 2*NW, NW);
  cast_f32_bf16<<<NW / 1024, 256, 0, stream>>>(Wo, wob,         NW);

  // QKV = xb @ wqkv^T : [4096, 3072]
  gemm_bt<false><<<dim3(3 * DM / 128, BATCH * SEQ / 128), 256, 0, stream>>>(
      xb, wqkv, (void*)qkv, BATCH * SEQ, 3 * DM, DM);

  rope_kernel<<<(BATCH * SEQ * NH * (DK / 2)) / 256, 256, 0, stream>>>(qkv, tp);

  flash_attn<<<dim3(SEQ / 64, NH, BATCH), 256, 0, stream>>>(qkv, attnb);

  // out = attnb @ wob^T : [4096, 1024] fp32
  gemm_bt<true><<<dim3(DM / 128, BATCH * SEQ / 128), 256, 0, stream>>>(
      attnb, wob, (void*)out, BATCH * SEQ, DM, DM);
}

// Round 3
// 151.413 us; speedup vs baseline: 2.1193x; 1.5860x over previous
//
#include <hip/hip_runtime.h>
#include <hip/hip_bf16.h>
#include <cstdint>
#include <cstddef>

// Problem constants
#define BATCH 2
#define SEQ   2048
#define DM    1024
#define NH    16
#define DK    64

typedef __attribute__((ext_vector_type(8)))  short short8;   // 8 bf16
typedef __attribute__((ext_vector_type(4)))  float f32x4;
typedef __attribute__((ext_vector_type(16))) float f32x16;   // 32x32 MFMA acc
typedef __attribute__((ext_vector_type(4)))  int   i32x4;
typedef __attribute__((ext_vector_type(2)))  int   i32x2;

// ---------------------------------------------------------------- helpers
__device__ __forceinline__ void gload_lds16(const __hip_bfloat16* g, __hip_bfloat16* l) {
  __builtin_amdgcn_global_load_lds((const __attribute__((address_space(1))) void*)g,
                                   (__attribute__((address_space(3))) void*)l, 16, 0, 0);
}

__device__ __forceinline__ int cvtpk_bf16(float lo, float hi) {
  int r;
  asm("v_cvt_pk_bf16_f32 %0, %1, %2" : "=v"(r) : "v"(lo), "v"(hi));
  return r;
}

// exchange value with lane^32 partner, VALU-only (permlane32_swap + select)
__device__ __forceinline__ float partner32(float x, int hi) {
  auto r = __builtin_amdgcn_permlane32_swap(__float_as_int(x), __float_as_int(x), false, false);
  // lanes 0-31: partner value is in r[1] (a.hi); lanes 32-63: in r[0] (b.lo)
  return __int_as_float(hi ? r[0] : r[1]);
}

// ---------------------------------------------------------------- cast fp32 -> bf16
__global__ void cast_f32_bf16(const float* __restrict__ src, __hip_bfloat16* __restrict__ dst, int n) {
  int i = (blockIdx.x * 256 + threadIdx.x) * 4;
  if (i >= n) return;
  float4 v = *(const float4*)(src + i);
  dst[i + 0] = __float2bfloat16(v.x);
  dst[i + 1] = __float2bfloat16(v.y);
  dst[i + 2] = __float2bfloat16(v.z);
  dst[i + 3] = __float2bfloat16(v.w);
}

// ---------------------------------------------------------------- GEMM: C[m,n] = sum_k A[m,k]*Bw[n,k]
// m97 structure: 128x128 tile, BK=32, 4 waves (2x2), each wave 64x64 = 4x4 16x16 frags.
// VSPLIT: cols >= 2048 are the V projection -> written TRANSPOSED to vt[b][h][d][s].
template<bool F32OUT, bool VSPLIT>
__global__ __launch_bounds__(256)
void gemm_bt(const __hip_bfloat16* __restrict__ A,
             const __hip_bfloat16* __restrict__ Bw,
             void* __restrict__ Cv, __hip_bfloat16* __restrict__ vt,
             int M, int N, int K, int ldc) {
  __shared__ __hip_bfloat16 As[128 * 32];
  __shared__ __hip_bfloat16 Bs[128 * 32];
  const int tid  = threadIdx.x;
  const int lane = tid & 63;
  const int w    = tid >> 6;        // wave 0..3
  const int wr   = w >> 1, wc = w & 1;
  const int g    = lane >> 4;       // 0..3  (k-subgroup)
  const int lr   = lane & 15;
  const int bm0  = blockIdx.y * 128;
  const int bn0  = blockIdx.x * 128;

  f32x4 acc[4][4] = {};

  const int strow = lane >> 2;      // 0..15 within chunk
  const int stcol = (lane & 3) * 8; // 0,8,16,24

  for (int kt = 0; kt < K; kt += 32) {
    #pragma unroll
    for (int it = 0; it < 2; ++it) {
      int c   = w * 2 + it;
      int row = c * 16 + strow;
      gload_lds16(A  + (size_t)(bm0 + row) * K + kt + stcol, As + row * 32 + stcol);
      gload_lds16(Bw + (size_t)(bn0 + row) * K + kt + stcol, Bs + row * 32 + stcol);
    }
    __syncthreads();
    short8 a[4], b[4];
    #pragma unroll
    for (int m = 0; m < 4; ++m)
      a[m] = *(const short8*)(As + (wr * 64 + m * 16 + lr) * 32 + g * 8);
    #pragma unroll
    for (int n = 0; n < 4; ++n)
      b[n] = *(const short8*)(Bs + (wc * 64 + n * 16 + lr) * 32 + g * 8);
    #pragma unroll
    for (int m = 0; m < 4; ++m)
      #pragma unroll
      for (int n = 0; n < 4; ++n)
        acc[m][n] = __builtin_amdgcn_mfma_f32_16x16x32_bf16(a[m], b[n], acc[m][n], 0, 0, 0);
    __syncthreads();
  }

  // epilogue: C layout col=lane&15, row=(lane>>4)*4+r
  if (VSPLIT && bn0 >= 2048) {
    // V slice -> vt[((b*NH+h)*DK+d)*SEQ + s], 4 consecutive s per acc frag -> 8B stores
    #pragma unroll
    for (int m = 0; m < 4; ++m)
      #pragma unroll
      for (int n = 0; n < 4; ++n) {
        int nn = bn0 + wc * 64 + n * 16 + lr - 2048;   // 0..1023
        int hd = nn >> 6, d = nn & 63;
        int m0 = bm0 + wr * 64 + m * 16 + g * 4;
        int bb = m0 >> 11, ss = m0 & 2047;
        i32x2 pk;
        pk[0] = cvtpk_bf16(acc[m][n][0], acc[m][n][1]);
        pk[1] = cvtpk_bf16(acc[m][n][2], acc[m][n][3]);
        *(i32x2*)(vt + ((size_t)(bb * NH + hd) * DK + d) * SEQ + ss) = pk;
      }
  } else {
    #pragma unroll
    for (int m = 0; m < 4; ++m)
      #pragma unroll
      for (int n = 0; n < 4; ++n) {
        int col = bn0 + wc * 64 + n * 16 + lr;
        #pragma unroll
        for (int r = 0; r < 4; ++r) {
          int row = bm0 + wr * 64 + m * 16 + g * 4 + r;
          float v = acc[m][n][r];
          if (F32OUT) ((float*)Cv)[(size_t)row * ldc + col] = v;
          else        ((__hip_bfloat16*)Cv)[(size_t)row * ldc + col] = __float2bfloat16(v);
        }
      }
  }
}

// ---------------------------------------------------------------- RoPE in place on QK buf [4096][2048]
// Q scaled by 0.125 * log2(e) so flash scores are in exp2 units directly.
__global__ void rope_kernel(__hip_bfloat16* __restrict__ qk, const int* __restrict__ pos) {
  int idx = blockIdx.x * 256 + threadIdx.x;
  if (idx >= BATCH * SEQ * NH * (DK / 2)) return;
  int m  = idx >> 9;          // row 0..4095
  int hp = idx & 511;
  int h  = hp >> 5;           // head
  int pk = hp & 31;           // pair index
  int s  = m & (SEQ - 1);
  float p   = (float)pos[s];
  float ang = p * exp2f(-(float)pk * 0.415241011860920f);
  float cv, sv;
  __sincosf(ang, &sv, &cv);
  const float QS = 0.125f * 1.4426950408889634f;
  size_t base = (size_t)m * 2048 + h * DK + 2 * pk;
  float q0 = __bfloat162float(qk[base]),          q1 = __bfloat162float(qk[base + 1]);
  qk[base]     = __float2bfloat16((q0 * cv - q1 * sv) * QS);
  qk[base + 1] = __float2bfloat16((q0 * sv + q1 * cv) * QS);
  float k0 = __bfloat162float(qk[base + 1024]),   k1 = __bfloat162float(qk[base + 1025]);
  qk[base + 1024] = __float2bfloat16(k0 * cv - k1 * sv);
  qk[base + 1025] = __float2bfloat16(k0 * sv + k1 * cv);
}

// ---------------------------------------------------------------- flash attention, swapped-operand 32x32
// grid (16 qblocks reversed, 16 heads, 2 batch) x 256 thr = 4 waves x 32 q-rows. KV tile 64, dbuf LDS.
// S^T = mfma32(K, Q): lane holds q=lane&31, k in regs -> softmax VALU-only (permlane32_swap).
// O^T = mfma32(V^T, P^T): rescale factor lane-local. V^T pre-transposed in global (vt).
__global__ __launch_bounds__(256)
void flash_attn(const __hip_bfloat16* __restrict__ qk,
                const __hip_bfloat16* __restrict__ vt,
                __hip_bfloat16* __restrict__ outb) {
  __shared__ __hip_bfloat16 Kls[2][64 * 64];   // K[k][d] swizzled
  __shared__ __hip_bfloat16 Vls[2][64 * 64];   // V^T[d][k] swizzled
  const int qb = (int)gridDim.x - 1 - blockIdx.x;
  const int hd = blockIdx.y, b = blockIdx.z;
  const int tid = threadIdx.x, lane = tid & 63, w = tid >> 6;
  const int hi = lane >> 5, ql = lane & 31;
  const int q0w = qb * 128 + w * 32;
  const int nt  = 2 * qb + 2;
  const int tmaxw = 2 * qb + (w >> 1);   // last tile this wave actually needs

  const __hip_bfloat16* Qb = qk + (size_t)(b * SEQ) * 2048 + hd * DK;
  const __hip_bfloat16* Kg = qk + (size_t)(b * SEQ) * 2048 + 1024 + hd * DK;
  const __hip_bfloat16* Vg = vt + (size_t)(b * NH + hd) * DK * SEQ;

  // Q fragments: B-operand, lane holds Q[q=ql][d=16c+8hi+j]
  short8 qf[4];
  #pragma unroll
  for (int c = 0; c < 4; ++c)
    qf[c] = *(const short8*)(Qb + (size_t)(q0w + ql) * 2048 + c * 16 + hi * 8);

  f32x16 o0 = {}, o1 = {};           // O^T acc: col=q (lane-local), rows = d
  float m_run = -1e30f, l_run = 0.f;

  // staging: thread -> row=tid>>2 (0..63), two 16B chunks per row per buffer
  const int srow = tid >> 2;
  const int sc0  = (tid & 3) * 8;    // elem col 0,8,16,24 (+32 second chunk)
  const int swz  = (srow & 7) << 3;  // element-level XOR swizzle (16B granular)

  short8 kr0, kr1, vr0, vr1;
  // prologue: tile 0
  kr0 = *(const short8*)(Kg + (size_t)srow * 2048 + sc0);
  kr1 = *(const short8*)(Kg + (size_t)srow * 2048 + sc0 + 32);
  vr0 = *(const short8*)(Vg + (size_t)srow * SEQ + sc0);
  vr1 = *(const short8*)(Vg + (size_t)srow * SEQ + sc0 + 32);
  *(short8*)(&Kls[0][srow * 64 + (sc0 ^ swz)])        = kr0;
  *(short8*)(&Kls[0][srow * 64 + ((sc0 + 32) ^ swz)]) = kr1;
  *(short8*)(&Vls[0][srow * 64 + (sc0 ^ swz)])        = vr0;
  *(short8*)(&Vls[0][srow * 64 + ((sc0 + 32) ^ swz)]) = vr1;

  for (int t = 0; t < nt; ++t) {
    const int cur = t & 1;
    // prefetch next tile into regs (latency hidden under compute)
    if (t + 1 < nt) {
      int r0 = (t + 1) * 64;
      kr0 = *(const short8*)(Kg + (size_t)(r0 + srow) * 2048 + sc0);
      kr1 = *(const short8*)(Kg + (size_t)(r0 + srow) * 2048 + sc0 + 32);
      vr0 = *(const short8*)(Vg + (size_t)srow * SEQ + r0 + sc0);
      vr1 = *(const short8*)(Vg + (size_t)srow * SEQ + r0 + sc0 + 32);
    }
    __syncthreads();   // buf[cur] writes visible; prev readers done with buf[cur^1]

    if (t <= tmaxw) {
      // ---- QK^T (swapped): S^T[k][q], 2 k-halves of 32
      f32x16 s0 = {}, s1 = {};
      #pragma unroll
      for (int c = 0; c < 4; ++c) {
        int col = (c * 16 + hi * 8) ^ ((ql & 7) << 3);
        short8 ka = *(const short8*)(&Kls[cur][ql * 64 + col]);
        short8 kb = *(const short8*)(&Kls[cur][(32 + ql) * 64 + col]);
        s0 = __builtin_amdgcn_mfma_f32_32x32x16_bf16(ka, qf[c], s0, 0, 0, 0);
        s1 = __builtin_amdgcn_mfma_f32_32x32x16_bf16(kb, qf[c], s1, 0, 0, 0);
      }

      // ---- causal mask (only tiles straddling the diagonal)
      if (t * 64 + 63 > q0w) {
        int qg = q0w + ql;
        #pragma unroll
        for (int r = 0; r < 16; ++r) {
          int krow = (r & 3) + 8 * (r >> 2) + 4 * hi;
          if (t * 64 + krow > qg)      s0[r] = -1e30f;
          if (t * 64 + 32 + krow > qg) s1[r] = -1e30f;
        }
      }

      // ---- online softmax, VALU-only (scores already in log2 units)
      float mx = s0[0];
      #pragma unroll
      for (int r = 1; r < 16; ++r) mx = fmaxf(mx, s0[r]);
      #pragma unroll
      for (int r = 0; r < 16; ++r) mx = fmaxf(mx, s1[r]);
      mx = fmaxf(mx, partner32(mx, hi));
      float mn  = fmaxf(m_run, mx);
      float fac = __builtin_amdgcn_exp2f(m_run - mn);
      m_run = mn;
      float sum = 0.f;
      #pragma unroll
      for (int r = 0; r < 16; ++r) { s0[r] = __builtin_amdgcn_exp2f(s0[r] - mn); sum += s0[r]; }
      #pragma unroll
      for (int r = 0; r < 16; ++r) { s1[r] = __builtin_amdgcn_exp2f(s1[r] - mn); sum += s1[r]; }
      sum += partner32(sum, hi);
      l_run = l_run * fac + sum;
      #pragma unroll
      for (int r = 0; r < 16; ++r) { o0[r] *= fac; o1[r] *= fac; }

      // ---- P^T f32 -> bf16 A/B fragments: 16 cvt_pk + 8 permlane32_swap (T12)
      short8 pf[4];
      #pragma unroll
      for (int kt = 0; kt < 2; ++kt) {
        const f32x16& sv = kt ? s1 : s0;
        #pragma unroll
        for (int u = 0; u < 2; ++u) {
          int wa0 = cvtpk_bf16(sv[8 * u + 0], sv[8 * u + 1]);
          int wa1 = cvtpk_bf16(sv[8 * u + 2], sv[8 * u + 3]);
          int wb0 = cvtpk_bf16(sv[8 * u + 4], sv[8 * u + 5]);
          int wb1 = cvtpk_bf16(sv[8 * u + 6], sv[8 * u + 7]);
          auto r0 = __builtin_amdgcn_permlane32_swap(wa0, wb0, false, false);
          auto r1 = __builtin_amdgcn_permlane32_swap(wa1, wb1, false, false);
          i32x4 fr; fr[0] = r0[0]; fr[1] = r1[0]; fr[2] = r0[1]; fr[3] = r1[1];
          pf[kt * 2 + u] = *(short8*)&fr;
        }
      }

      // ---- PV (swapped): O^T[d][q] += V^T[d][k] * P^T[k][q]
      #pragma unroll
      for (int cc = 0; cc < 4; ++cc) {
        int col = (cc * 16 + hi * 8) ^ ((ql & 7) << 3);
        short8 va = *(const short8*)(&Vls[cur][ql * 64 + col]);
        short8 vb = *(const short8*)(&Vls[cur][(32 + ql) * 64 + col]);
        o0 = __builtin_amdgcn_mfma_f32_32x32x16_bf16(va, pf[cc], o0, 0, 0, 0);
        o1 = __builtin_amdgcn_mfma_f32_32x32x16_bf16(vb, pf[cc], o1, 0, 0, 0);
      }
    }

    // ---- write prefetched tile into the other buffer (safe: barrier above separated prev readers)
    if (t + 1 < nt) {
      const int nxt = cur ^ 1;
      *(short8*)(&Kls[nxt][srow * 64 + (sc0 ^ swz)])        = kr0;
      *(short8*)(&Kls[nxt][srow * 64 + ((sc0 + 32) ^ swz)]) = kr1;
      *(short8*)(&Vls[nxt][srow * 64 + (sc0 ^ swz)])        = vr0;
      *(short8*)(&Vls[nxt][srow * 64 + ((sc0 + 32) ^ swz)]) = vr1;
    }
  }

  // ---- epilogue: O^T rows are d = (r&3)+8*(r>>2)+4*hi (+32 for o1); 4 consecutive d per quad -> 8B stores
  float inv = 1.f / l_run;
  __hip_bfloat16* orow = outb + (size_t)(b * SEQ + q0w + ql) * DM + hd * DK;
  #pragma unroll
  for (int dt = 0; dt < 2; ++dt) {
    const f32x16& oa = dt ? o1 : o0;
    #pragma unroll
    for (int a = 0; a < 4; ++a) {
      int d0 = dt * 32 + a * 8 + hi * 4;
      i32x2 pk;
      pk[0] = cvtpk_bf16(oa[4 * a + 0] * inv, oa[4 * a + 1] * inv);
      pk[1] = cvtpk_bf16(oa[4 * a + 2] * inv, oa[4 * a + 3] * inv);
      *(i32x2*)(orow + d0) = pk;
    }
  }
}

// ---------------------------------------------------------------- launch
extern "C" void kernel_launch(void* const* d_in, const int* in_sizes, int n_in,
                              void* d_out, int out_size, void* d_ws, size_t ws_size,
                              hipStream_t stream) {
  const float* x  = (const float*)d_in[0];
  const float* Wq = (const float*)d_in[1];
  const float* Wk = (const float*)d_in[2];
  const float* Wv = (const float*)d_in[3];
  const float* Wo = (const float*)d_in[4];
  const int*   tp = (const int*)d_in[5];
  float* out = (float*)d_out;

  char* ws = (char*)d_ws;
  __hip_bfloat16* xb    = (__hip_bfloat16*)(ws);                 // [4096][1024]  8 MB
  __hip_bfloat16* wqkv  = (__hip_bfloat16*)(ws + (8u  << 20));   // [3072][1024]  6 MB
  __hip_bfloat16* wob   = (__hip_bfloat16*)(ws + (14u << 20));   // [1024][1024]  2 MB
  __hip_bfloat16* qkbuf = (__hip_bfloat16*)(ws + (16u << 20));   // [4096][2048] 16 MB (Q|K)
  __hip_bfloat16* vtbuf = (__hip_bfloat16*)(ws + (32u << 20));   // [2][16][64][2048] 8 MB (V^T)
  __hip_bfloat16* attnb = (__hip_bfloat16*)(ws + (40u << 20));   // [4096][1024]  8 MB

  const int NX = BATCH * SEQ * DM;   // 4194304
  const int NW = DM * DM;            // 1048576

  cast_f32_bf16<<<NX / 1024, 256, 0, stream>>>(x,  xb,          NX);
  cast_f32_bf16<<<NW / 1024, 256, 0, stream>>>(Wq, wqkv,        NW);
  cast_f32_bf16<<<NW / 1024, 256, 0, stream>>>(Wk, wqkv + NW,   NW);
  cast_f32_bf16<<<NW / 1024, 256, 0, stream>>>(Wv, wqkv + 2*NW, NW);
  cast_f32_bf16<<<NW / 1024, 256, 0, stream>>>(Wo, wob,         NW);

  // QKV = xb @ wqkv^T : Q,K -> qkbuf (ldc=2048), V -> vtbuf transposed
  gemm_bt<false, true><<<dim3(3 * DM / 128, BATCH * SEQ / 128), 256, 0, stream>>>(
      xb, wqkv, (void*)qkbuf, vtbuf, BATCH * SEQ, 3 * DM, DM, 2048);

  rope_kernel<<<(BATCH * SEQ * NH * (DK / 2)) / 256, 256, 0, stream>>>(qkbuf, tp);

  flash_attn<<<dim3(SEQ / 128, NH, BATCH), 256, 0, stream>>>(qkbuf, vtbuf, attnb);

  // out = attnb @ wob^T : [4096, 1024] fp32
  gemm_bt<true, false><<<dim3(DM / 128, BATCH * SEQ / 128), 256, 0, stream>>>(
      attnb, wob, (void*)out, nullptr, BATCH * SEQ, DM, DM, DM);
}

// Round 4
// 125.432 us; speedup vs baseline: 2.5583x; 1.2071x over previous
//
#include <hip/hip_runtime.h>
#include <hip/hip_bf16.h>
#include <cstdint>
#include <cstddef>

// Problem constants
#define BATCH 2
#define SEQ   2048
#define DM    1024
#define NH    16
#define DK    64

typedef __attribute__((ext_vector_type(8)))  short short8;   // 8 bf16
typedef __attribute__((ext_vector_type(4)))  float f32x4;
typedef __attribute__((ext_vector_type(16))) float f32x16;   // 32x32 MFMA acc
typedef __attribute__((ext_vector_type(4)))  int   i32x4;
typedef __attribute__((ext_vector_type(2)))  int   i32x2;

// ---------------------------------------------------------------- helpers
__device__ __forceinline__ void gload_lds16(const __hip_bfloat16* g, __hip_bfloat16* l) {
  __builtin_amdgcn_global_load_lds((const __attribute__((address_space(1))) void*)g,
                                   (__attribute__((address_space(3))) void*)l, 16, 0, 0);
}

__device__ __forceinline__ int cvtpk_bf16(float lo, float hi) {
  int r;
  asm("v_cvt_pk_bf16_f32 %0, %1, %2" : "=v"(r) : "v"(lo), "v"(hi));
  return r;
}

// exchange value with lane^32 partner, VALU-only (permlane32_swap + select)
__device__ __forceinline__ float partner32(float x, int hi) {
  auto r = __builtin_amdgcn_permlane32_swap(__float_as_int(x), __float_as_int(x), false, false);
  return __int_as_float(hi ? r[0] : r[1]);
}

// ---------------------------------------------------------------- fused cast fp32 -> bf16
// dst regions are contiguous in ws: [xb 4M elem][wqkv 3M elem][wob 1M elem] = 8M bf16.
__global__ void cast_all(const float* __restrict__ x,  const float* __restrict__ Wq,
                         const float* __restrict__ Wk, const float* __restrict__ Wv,
                         const float* __restrict__ Wo, __hip_bfloat16* __restrict__ dst) {
  const int NX = BATCH * SEQ * DM;               // 4194304
  size_t i = ((size_t)blockIdx.x * 256 + threadIdx.x) * 4;
  const float* s;
  if (i < (size_t)NX) {
    s = x + i;
  } else {
    size_t j = i - NX;
    int wsel = (int)(j >> 20);                   // 1M elements per weight
    size_t o = j & ((1u << 20) - 1);
    s = (wsel == 0 ? Wq : wsel == 1 ? Wk : wsel == 2 ? Wv : Wo) + o;
  }
  float4 v = *(const float4*)s;
  i32x2 pk;
  pk[0] = cvtpk_bf16(v.x, v.y);
  pk[1] = cvtpk_bf16(v.z, v.w);
  *(i32x2*)(dst + i) = pk;
}

// ---------------------------------------------------------------- GEMM: C[m,n] = sum_k A[m,k]*Bw[n,k]
// m97 structure: 128x128 tile, BK=32, 4 waves (2x2), each wave 64x64 = 4x4 16x16 frags.
// VSPLIT: cols >= 2048 are the V projection -> written TRANSPOSED to vt[b][h][d][s].
template<bool F32OUT, bool VSPLIT>
__global__ __launch_bounds__(256)
void gemm_bt(const __hip_bfloat16* __restrict__ A,
             const __hip_bfloat16* __restrict__ Bw,
             void* __restrict__ Cv, __hip_bfloat16* __restrict__ vt,
             int M, int N, int K, int ldc) {
  __shared__ __hip_bfloat16 As[128 * 32];
  __shared__ __hip_bfloat16 Bs[128 * 32];
  const int tid  = threadIdx.x;
  const int lane = tid & 63;
  const int w    = tid >> 6;        // wave 0..3
  const int wr   = w >> 1, wc = w & 1;
  const int g    = lane >> 4;       // 0..3  (k-subgroup)
  const int lr   = lane & 15;
  const int bm0  = blockIdx.y * 128;
  const int bn0  = blockIdx.x * 128;

  f32x4 acc[4][4] = {};

  const int strow = lane >> 2;      // 0..15 within chunk
  const int stcol = (lane & 3) * 8; // 0,8,16,24

  for (int kt = 0; kt < K; kt += 32) {
    #pragma unroll
    for (int it = 0; it < 2; ++it) {
      int c   = w * 2 + it;
      int row = c * 16 + strow;
      gload_lds16(A  + (size_t)(bm0 + row) * K + kt + stcol, As + row * 32 + stcol);
      gload_lds16(Bw + (size_t)(bn0 + row) * K + kt + stcol, Bs + row * 32 + stcol);
    }
    __syncthreads();
    short8 a[4], b[4];
    #pragma unroll
    for (int m = 0; m < 4; ++m)
      a[m] = *(const short8*)(As + (wr * 64 + m * 16 + lr) * 32 + g * 8);
    #pragma unroll
    for (int n = 0; n < 4; ++n)
      b[n] = *(const short8*)(Bs + (wc * 64 + n * 16 + lr) * 32 + g * 8);
    #pragma unroll
    for (int m = 0; m < 4; ++m)
      #pragma unroll
      for (int n = 0; n < 4; ++n)
        acc[m][n] = __builtin_amdgcn_mfma_f32_16x16x32_bf16(a[m], b[n], acc[m][n], 0, 0, 0);
    __syncthreads();
  }

  // epilogue: C layout col=lane&15, row=(lane>>4)*4+r
  if (VSPLIT && bn0 >= 2048) {
    #pragma unroll
    for (int m = 0; m < 4; ++m)
      #pragma unroll
      for (int n = 0; n < 4; ++n) {
        int nn = bn0 + wc * 64 + n * 16 + lr - 2048;   // 0..1023
        int hd = nn >> 6, d = nn & 63;
        int m0 = bm0 + wr * 64 + m * 16 + g * 4;
        int bb = m0 >> 11, ss = m0 & 2047;
        i32x2 pk;
        pk[0] = cvtpk_bf16(acc[m][n][0], acc[m][n][1]);
        pk[1] = cvtpk_bf16(acc[m][n][2], acc[m][n][3]);
        *(i32x2*)(vt + ((size_t)(bb * NH + hd) * DK + d) * SEQ + ss) = pk;
      }
  } else {
    #pragma unroll
    for (int m = 0; m < 4; ++m)
      #pragma unroll
      for (int n = 0; n < 4; ++n) {
        int col = bn0 + wc * 64 + n * 16 + lr;
        #pragma unroll
        for (int r = 0; r < 4; ++r) {
          int row = bm0 + wr * 64 + m * 16 + g * 4 + r;
          float v = acc[m][n][r];
          if (F32OUT) ((float*)Cv)[(size_t)row * ldc + col] = v;
          else        ((__hip_bfloat16*)Cv)[(size_t)row * ldc + col] = __float2bfloat16(v);
        }
      }
  }
}

// ---------------------------------------------------------------- RoPE in place on QK buf [4096][2048]
// Q scaled by 0.125 * log2(e) so flash scores are in exp2 units directly.
__global__ void rope_kernel(__hip_bfloat16* __restrict__ qk, const int* __restrict__ pos) {
  int idx = blockIdx.x * 256 + threadIdx.x;
  if (idx >= BATCH * SEQ * NH * (DK / 2)) return;
  int m  = idx >> 9;          // row 0..4095
  int hp = idx & 511;
  int h  = hp >> 5;           // head
  int pk = hp & 31;           // pair index
  int s  = m & (SEQ - 1);
  float p   = (float)pos[s];
  float ang = p * exp2f(-(float)pk * 0.415241011860920f);
  float cv, sv;
  __sincosf(ang, &sv, &cv);
  const float QS = 0.125f * 1.4426950408889634f;
  size_t base = (size_t)m * 2048 + h * DK + 2 * pk;
  float q0 = __bfloat162float(qk[base]),          q1 = __bfloat162float(qk[base + 1]);
  qk[base]     = __float2bfloat16((q0 * cv - q1 * sv) * QS);
  qk[base + 1] = __float2bfloat16((q0 * sv + q1 * cv) * QS);
  float k0 = __bfloat162float(qk[base + 1024]),   k1 = __bfloat162float(qk[base + 1025]);
  qk[base + 1024] = __float2bfloat16(k0 * cv - k1 * sv);
  qk[base + 1025] = __float2bfloat16(k0 * sv + k1 * cv);
}

// ---------------------------------------------------------------- flash attention, swapped-operand 32x32
// Pair-balanced: grid (8, 16, 2) x 512 thr = 8 waves. Waves 0-3 own q-chunk qbh=15-pi,
// waves 4-7 own qbl=pi; qbl's KV range is a prefix of qbh's so the staged K/V tiles are shared.
// Every block does (2*qbh+2)+(2*qbl+2) = 34 wave-tile-units -> perfect CU balance.
// S^T = mfma32(K, Q): lane holds q=lane&31 -> softmax VALU-only (permlane32_swap).
// O^T = mfma32(V^T, P^T). V^T pre-transposed in global (vt).
__global__ __launch_bounds__(512)
void flash_attn(const __hip_bfloat16* __restrict__ qk,
                const __hip_bfloat16* __restrict__ vt,
                __hip_bfloat16* __restrict__ outb) {
  __shared__ __hip_bfloat16 Kls[2][64 * 64];   // K[k][d] swizzled
  __shared__ __hip_bfloat16 Vls[2][64 * 64];   // V^T[d][k] swizzled
  const int pi = blockIdx.x;                   // pair index 0..7
  const int NQB = SEQ / 128;                   // 16
  const int qbh = NQB - 1 - pi, qbl = pi;
  const int hd = blockIdx.y, b = blockIdx.z;
  const int tid = threadIdx.x, lane = tid & 63, w = tid >> 6;   // w 0..7
  const int wh = w & 3;
  const int qb_eff = (w < 4) ? qbh : qbl;
  const int hi = lane >> 5, ql = lane & 31;
  const int q0w = qb_eff * 128 + wh * 32;
  const int nt  = 2 * qbh + 2;                 // tiles staged (max over both halves)
  const int tmaxw = 2 * qb_eff + (wh >> 1);    // last tile this wave computes

  const __hip_bfloat16* Qb = qk + (size_t)(b * SEQ) * 2048 + hd * DK;
  const __hip_bfloat16* Kg = qk + (size_t)(b * SEQ) * 2048 + 1024 + hd * DK;
  const __hip_bfloat16* Vg = vt + (size_t)(b * NH + hd) * DK * SEQ;

  // Q fragments: B-operand, lane holds Q[q=ql][d=16c+8hi+j]
  short8 qf[4];
  #pragma unroll
  for (int c = 0; c < 4; ++c)
    qf[c] = *(const short8*)(Qb + (size_t)(q0w + ql) * 2048 + c * 16 + hi * 8);

  f32x16 o0 = {}, o1 = {};
  float m_run = -1e30f, l_run = 0.f;

  // staging: 512 threads x 16B = one 64x64 bf16 tile per tensor
  const int srow = tid >> 3;            // 0..63
  const int sc0  = (tid & 7) * 8;       // 0..56
  const int swz  = (srow & 7) << 3;

  short8 kr, vr;
  kr = *(const short8*)(Kg + (size_t)srow * 2048 + sc0);
  vr = *(const short8*)(Vg + (size_t)srow * SEQ + sc0);
  *(short8*)(&Kls[0][srow * 64 + (sc0 ^ swz)]) = kr;
  *(short8*)(&Vls[0][srow * 64 + (sc0 ^ swz)]) = vr;

  for (int t = 0; t < nt; ++t) {
    const int cur = t & 1;
    if (t + 1 < nt) {
      int r0 = (t + 1) * 64;
      kr = *(const short8*)(Kg + (size_t)(r0 + srow) * 2048 + sc0);
      vr = *(const short8*)(Vg + (size_t)srow * SEQ + r0 + sc0);
    }
    __syncthreads();

    if (t <= tmaxw) {
      // ---- QK^T (swapped): S^T[k][q], 2 k-halves of 32
      f32x16 s0 = {}, s1 = {};
      __builtin_amdgcn_s_setprio(1);
      #pragma unroll
      for (int c = 0; c < 4; ++c) {
        int col = (c * 16 + hi * 8) ^ ((ql & 7) << 3);
        short8 ka = *(const short8*)(&Kls[cur][ql * 64 + col]);
        short8 kb = *(const short8*)(&Kls[cur][(32 + ql) * 64 + col]);
        s0 = __builtin_amdgcn_mfma_f32_32x32x16_bf16(ka, qf[c], s0, 0, 0, 0);
        s1 = __builtin_amdgcn_mfma_f32_32x32x16_bf16(kb, qf[c], s1, 0, 0, 0);
      }
      __builtin_amdgcn_s_setprio(0);

      // ---- causal mask (only the straddling tile)
      if (t * 64 + 63 > q0w) {
        int qg = q0w + ql;
        #pragma unroll
        for (int r = 0; r < 16; ++r) {
          int krow = (r & 3) + 8 * (r >> 2) + 4 * hi;
          if (t * 64 + krow > qg)      s0[r] = -1e30f;
          if (t * 64 + 32 + krow > qg) s1[r] = -1e30f;
        }
      }

      // ---- online softmax, VALU-only (scores already in log2 units)
      float mx = s0[0];
      #pragma unroll
      for (int r = 1; r < 16; ++r) mx = fmaxf(mx, s0[r]);
      #pragma unroll
      for (int r = 0; r < 16; ++r) mx = fmaxf(mx, s1[r]);
      mx = fmaxf(mx, partner32(mx, hi));

      // defer-max (T13): only rescale when the max grew by > 8 (log2 units, P <= 256)
      if (!__all(mx <= m_run + 8.f)) {
        float mn  = fmaxf(m_run, mx);
        float fac = __builtin_amdgcn_exp2f(m_run - mn);
        m_run = mn;
        l_run *= fac;
        #pragma unroll
        for (int r = 0; r < 16; ++r) { o0[r] *= fac; o1[r] *= fac; }
      }
      float sum = 0.f;
      #pragma unroll
      for (int r = 0; r < 16; ++r) { s0[r] = __builtin_amdgcn_exp2f(s0[r] - m_run); sum += s0[r]; }
      #pragma unroll
      for (int r = 0; r < 16; ++r) { s1[r] = __builtin_amdgcn_exp2f(s1[r] - m_run); sum += s1[r]; }
      sum += partner32(sum, hi);
      l_run += sum;

      // ---- P^T f32 -> bf16 A/B fragments: 16 cvt_pk + 8 permlane32_swap (T12)
      short8 pf[4];
      #pragma unroll
      for (int kt = 0; kt < 2; ++kt) {
        const f32x16& sv = kt ? s1 : s0;
        #pragma unroll
        for (int u = 0; u < 2; ++u) {
          int wa0 = cvtpk_bf16(sv[8 * u + 0], sv[8 * u + 1]);
          int wa1 = cvtpk_bf16(sv[8 * u + 2], sv[8 * u + 3]);
          int wb0 = cvtpk_bf16(sv[8 * u + 4], sv[8 * u + 5]);
          int wb1 = cvtpk_bf16(sv[8 * u + 6], sv[8 * u + 7]);
          auto r0 = __builtin_amdgcn_permlane32_swap(wa0, wb0, false, false);
          auto r1 = __builtin_amdgcn_permlane32_swap(wa1, wb1, false, false);
          i32x4 fr; fr[0] = r0[0]; fr[1] = r1[0]; fr[2] = r0[1]; fr[3] = r1[1];
          pf[kt * 2 + u] = *(short8*)&fr;
        }
      }

      // ---- PV (swapped): O^T[d][q] += V^T[d][k] * P^T[k][q]
      __builtin_amdgcn_s_setprio(1);
      #pragma unroll
      for (int cc = 0; cc < 4; ++cc) {
        int col = (cc * 16 + hi * 8) ^ ((ql & 7) << 3);
        short8 va = *(const short8*)(&Vls[cur][ql * 64 + col]);
        short8 vb = *(const short8*)(&Vls[cur][(32 + ql) * 64 + col]);
        o0 = __builtin_amdgcn_mfma_f32_32x32x16_bf16(va, pf[cc], o0, 0, 0, 0);
        o1 = __builtin_amdgcn_mfma_f32_32x32x16_bf16(vb, pf[cc], o1, 0, 0, 0);
      }
      __builtin_amdgcn_s_setprio(0);
    }

    if (t + 1 < nt) {
      const int nxt = cur ^ 1;
      *(short8*)(&Kls[nxt][srow * 64 + (sc0 ^ swz)]) = kr;
      *(short8*)(&Vls[nxt][srow * 64 + (sc0 ^ swz)]) = vr;
    }
  }

  // ---- epilogue: O^T rows are d = (r&3)+8*(r>>2)+4*hi (+32 for o1)
  float inv = 1.f / l_run;
  __hip_bfloat16* orow = outb + (size_t)(b * SEQ + q0w + ql) * DM + hd * DK;
  #pragma unroll
  for (int dt = 0; dt < 2; ++dt) {
    const f32x16& oa = dt ? o1 : o0;
    #pragma unroll
    for (int a = 0; a < 4; ++a) {
      int d0 = dt * 32 + a * 8 + hi * 4;
      i32x2 pk;
      pk[0] = cvtpk_bf16(oa[4 * a + 0] * inv, oa[4 * a + 1] * inv);
      pk[1] = cvtpk_bf16(oa[4 * a + 2] * inv, oa[4 * a + 3] * inv);
      *(i32x2*)(orow + d0) = pk;
    }
  }
}

// ---------------------------------------------------------------- launch
extern "C" void kernel_launch(void* const* d_in, const int* in_sizes, int n_in,
                              void* d_out, int out_size, void* d_ws, size_t ws_size,
                              hipStream_t stream) {
  const float* x  = (const float*)d_in[0];
  const float* Wq = (const float*)d_in[1];
  const float* Wk = (const float*)d_in[2];
  const float* Wv = (const float*)d_in[3];
  const float* Wo = (const float*)d_in[4];
  const int*   tp = (const int*)d_in[5];
  float* out = (float*)d_out;

  char* ws = (char*)d_ws;
  __hip_bfloat16* xb    = (__hip_bfloat16*)(ws);                 // [4096][1024]  8 MB
  __hip_bfloat16* wqkv  = (__hip_bfloat16*)(ws + (8u  << 20));   // [3072][1024]  6 MB
  __hip_bfloat16* wob   = (__hip_bfloat16*)(ws + (14u << 20));   // [1024][1024]  2 MB
  __hip_bfloat16* qkbuf = (__hip_bfloat16*)(ws + (16u << 20));   // [4096][2048] 16 MB (Q|K)
  __hip_bfloat16* vtbuf = (__hip_bfloat16*)(ws + (32u << 20));   // [2][16][64][2048] 8 MB (V^T)
  __hip_bfloat16* attnb = (__hip_bfloat16*)(ws + (40u << 20));   // [4096][1024]  8 MB

  // fused cast: 8M elements, dst contiguous from ws
  cast_all<<<8192, 256, 0, stream>>>(x, Wq, Wk, Wv, Wo, xb);

  // QKV = xb @ wqkv^T : Q,K -> qkbuf (ldc=2048), V -> vtbuf transposed
  gemm_bt<false, true><<<dim3(3 * DM / 128, BATCH * SEQ / 128), 256, 0, stream>>>(
      xb, wqkv, (void*)qkbuf, vtbuf, BATCH * SEQ, 3 * DM, DM, 2048);

  rope_kernel<<<(BATCH * SEQ * NH * (DK / 2)) / 256, 256, 0, stream>>>(qkbuf, tp);

  flash_attn<<<dim3(SEQ / 256, NH, BATCH), 512, 0, stream>>>(qkbuf, vtbuf, attnb);

  // out = attnb @ wob^T : [4096, 1024] fp32
  gemm_bt<true, false><<<dim3(DM / 128, BATCH * SEQ / 128), 256, 0, stream>>>(
      attnb, wob, (void*)out, nullptr, BATCH * SEQ, DM, DM, DM);
}